// Round 10
// baseline (91.518 us; speedup 1.0000x reference)
//
#include <hip/hip_runtime.h>
#include <hip/hip_bf16.h>

// SimpleRNN(tanh) + Dense(5) + softmax, fused. B=8192, T=187, D=1, H=128, C=5.
//
// R10 == R9 resubmitted unchanged after an infra failure (container refused
// first RPC; source audited clean: 44.8 KB LDS, bounded indices, no UB).
//
// R9: depth-2 stream pipeline. Each block: TWO independent 16-batch tiles
// (A,B) on the same 8 waves; one barrier per step serves both exchanges, so
// per-step fixed latency (barrier + LDS + chains) amortizes over 2x compute.
// Grid 256 x 512 thr -> 1 block/CU, 2 waves/SIMD, 4 indep MFMA chains/wave.
// Issue diet: bias rides the MFMA C operand (no zero-init); U,W,b prescaled
// by 2*log2(e) so tanh = exp2, add, rcp, fma (no mul).
//
// Recurrence (validated R6/R8): transposed h_pre^T = U^T h^T via
// mfma_f32_16x16x32_f16, wave w owns rows [16w,16w+16), produces
// half-fragment (T=w>>1, half=w&1) -> double-buffered LDS. D-frag of step s
// == B-frag of step s+1 in-lane. No dynamic register-array indexing.

#define BT 8192
#define TS 187
#define HD 128
#define NC 5

typedef float    f32x4  __attribute__((ext_vector_type(4)));
typedef _Float16 f16x8  __attribute__((ext_vector_type(8)));
typedef __fp16   fp16x2 __attribute__((ext_vector_type(2)));   // cvt_pkrtz return
typedef unsigned int u32;
typedef u32      u32x2  __attribute__((ext_vector_type(2)));

// All of U, W, b prescaled by PRE = 2*log2(e): MFMA output is v' = PRE*v,
// and tanh(v) = 1 - 2/(2^(v') + 1).
#define PRE 2.885390081777927f

__device__ __forceinline__ float exp2_fast(float v) {
#if __has_builtin(__builtin_amdgcn_exp2f)
    return __builtin_amdgcn_exp2f(v);
#else
    return exp2f(v);
#endif
}

__device__ __forceinline__ float tanh_pre(float vp) {
    // vp = PRE * v;  tanh(v) = 1 - 2/(2^vp + 1); exact at +-inf, no NaN.
    float e = exp2_fast(vp);
    float r = __builtin_amdgcn_rcpf(e + 1.0f);
    return fmaf(-2.0f, r, 1.0f);
}

__device__ __forceinline__ u32 pk16(float a, float b) {
    fp16x2 p = __builtin_amdgcn_cvt_pkrtz(a, b);
    return __builtin_bit_cast(u32, p);
}

union frag_u { f16x8 v; u32 w[4]; };

__device__ __forceinline__ void pin_frag(f16x8& f) {
    frag_u pu; pu.v = f;
    asm volatile("" : "+v"(pu.w[0]), "+v"(pu.w[1]), "+v"(pu.w[2]), "+v"(pu.w[3]));
    f = pu.v;
}

__global__ __launch_bounds__(512, 2)
void rnn_fused(const float* __restrict__ xg, const float* __restrict__ wg,
               const float* __restrict__ ug, const float* __restrict__ bg,
               const float* __restrict__ wdg, const float* __restrict__ bdg,
               float* __restrict__ outg)
{
    __shared__ u32   xbA[2][4][64][4];  // tile A h-frag exchange, 8 KB
    __shared__ u32   xbB[2][4][64][4];  // tile B, 8 KB
    __shared__ float xs2[2][TS][16];    // staged x, [tile][time][batch col]
    __shared__ float lgA[8][16][NC];    // head partials
    __shared__ float lgB[8][16][NC];

    const int tid  = threadIdx.x;
    const int w    = tid >> 6;          // wave 0..7 owns j in [16w, 16w+16)
    const int lane = tid & 63;
    const int l15  = lane & 15;         // batch col / j col for A-frag
    const int l4   = lane >> 4;         // 0..3
    const int b0   = blockIdx.x * 32;   // 32 batch rows: A=b0..+15, B=b0+16..+31
    const int Tw   = w >> 1;            // fragment this wave feeds
    const int hw   = w & 1;             // which half (dwords 2hw, 2hw+1)

    // ---- stage x for both tiles (one-time, coalesced)
    #pragma unroll
    for (int r = 0; r < 12; ++r) {
        const int idx = r * 512 + tid;          // 12*512 = 6144 = 32*192
        const int bb  = idx / 192;              // 0..31
        const int ss  = idx % 192;
        if (ss < TS)
            xs2[bb >> 4][ss][bb & 15] = xg[(long)(b0 + bb) * TS + ss];
    }

    // ---- U^T fragments (shared by both tiles), prescaled fp16.
    //   m = l15 -> j = 16w + l15 ; elem e -> i = 32T + 16(e>>2) + 4l4 + (e&3)
    f16x8 uf0, uf1, uf2, uf3;
    {
        const int j = 16*w + l15;
        #pragma unroll
        for (int e = 0; e < 8; ++e) {
            const int i = 16*(e>>2) + 4*l4 + (e&3);
            uf0[e] = (_Float16)(PRE * ug[(i      )*HD + j]);
            uf1[e] = (_Float16)(PRE * ug[(i + 32 )*HD + j]);
            uf2[e] = (_Float16)(PRE * ug[(i + 64 )*HD + j]);
            uf3[e] = (_Float16)(PRE * ug[(i + 96 )*HD + j]);
        }
    }
    pin_frag(uf0); pin_frag(uf1); pin_frag(uf2); pin_frag(uf3);

    // ---- per-lane W, b (prescaled); b rides the MFMA C operand
    float wv[4]; f32x4 bvv;
    #pragma unroll
    for (int q = 0; q < 4; ++q) {
        const int j = 16*w + 4*l4 + q;
        wv[q]  = PRE * wg[j];
        bvv[q] = PRE * bg[j];
    }

    // ---- state: h fragments for both tiles, h0 = 0
    f16x8 hA0 = (f16x8)(_Float16)0.0f;
    f16x8 hA1 = hA0, hA2 = hA0, hA3 = hA0;
    f16x8 hB0 = hA0, hB1 = hA0, hB2 = hA0, hB3 = hA0;

    __syncthreads();                    // xs2 ready
    float xvA = xs2[0][0][l15];
    float xvB = xs2[1][0][l15];

    f32x4 accA, accB;   // post-tanh h persists for the epilogue

    // One recurrence step for BOTH tiles; BUF compile-time.
#define STEP(BUF, SN)                                                        \
    {                                                                        \
        const float xAn = xs2[0][(SN)][l15];                                 \
        const float xBn = xs2[1][(SN)][l15];                                 \
        f32x4 a0, a1, c0, c1;                                                \
        _Pragma("unroll") for (int q = 0; q < 4; ++q) {                      \
            a0[q] = xvA * wv[q]; c0[q] = xvB * wv[q];                        \
        }                                                                    \
        a0 = __builtin_amdgcn_mfma_f32_16x16x32_f16(uf0, hA0, a0,  0, 0, 0); \
        c0 = __builtin_amdgcn_mfma_f32_16x16x32_f16(uf0, hB0, c0,  0, 0, 0); \
        a1 = __builtin_amdgcn_mfma_f32_16x16x32_f16(uf2, hA2, bvv, 0, 0, 0); \
        c1 = __builtin_amdgcn_mfma_f32_16x16x32_f16(uf2, hB2, bvv, 0, 0, 0); \
        a0 = __builtin_amdgcn_mfma_f32_16x16x32_f16(uf1, hA1, a0,  0, 0, 0); \
        c0 = __builtin_amdgcn_mfma_f32_16x16x32_f16(uf1, hB1, c0,  0, 0, 0); \
        a1 = __builtin_amdgcn_mfma_f32_16x16x32_f16(uf3, hA3, a1,  0, 0, 0); \
        c1 = __builtin_amdgcn_mfma_f32_16x16x32_f16(uf3, hB3, c1,  0, 0, 0); \
        _Pragma("unroll") for (int q = 0; q < 4; ++q) {                      \
            accA[q] = tanh_pre(a0[q] + a1[q]);                               \
            accB[q] = tanh_pre(c0[q] + c1[q]);                               \
        }                                                                    \
        u32x2 pA, pB;                                                        \
        pA[0] = pk16(accA[0], accA[1]); pA[1] = pk16(accA[2], accA[3]);      \
        pB[0] = pk16(accB[0], accB[1]); pB[1] = pk16(accB[2], accB[3]);      \
        *(u32x2*)&xbA[(BUF)][Tw][lane][2*hw] = pA;                           \
        *(u32x2*)&xbB[(BUF)][Tw][lane][2*hw] = pB;                           \
        __syncthreads();                                                     \
        hA0 = *(const f16x8*)&xbA[(BUF)][0][lane][0];                        \
        hA1 = *(const f16x8*)&xbA[(BUF)][1][lane][0];                        \
        hA2 = *(const f16x8*)&xbA[(BUF)][2][lane][0];                        \
        hA3 = *(const f16x8*)&xbA[(BUF)][3][lane][0];                        \
        hB0 = *(const f16x8*)&xbB[(BUF)][0][lane][0];                        \
        hB1 = *(const f16x8*)&xbB[(BUF)][1][lane][0];                        \
        hB2 = *(const f16x8*)&xbB[(BUF)][2][lane][0];                        \
        hB3 = *(const f16x8*)&xbB[(BUF)][3][lane][0];                        \
        xvA = xAn; xvB = xBn;                                                \
    }

    for (int k = 0; k < 93; ++k) {      // steps 0..185 as 93 unrolled pairs
        STEP(0, 2*k + 1);
        STEP(1, 2*k + 2);
    }
    STEP(0, TS - 1);                    // step 186 (dummy prefetch)
#undef STEP

    // ---- head: logits = h @ Wd + bd ; softmax over 5 (both tiles) ----
    float pA[NC], pB[NC];
    #pragma unroll
    for (int c = 0; c < NC; ++c) { pA[c] = 0.0f; pB[c] = 0.0f; }
    #pragma unroll
    for (int q = 0; q < 4; ++q) {
        const int j = 16*w + 4*l4 + q;
        #pragma unroll
        for (int c = 0; c < NC; ++c) {
            const float wd = wdg[j*NC + c];
            pA[c] = fmaf(accA[q], wd, pA[c]);
            pB[c] = fmaf(accB[q], wd, pB[c]);
        }
    }
    #pragma unroll
    for (int c = 0; c < NC; ++c) {      // reduce over l4 groups
        pA[c] += __shfl_xor(pA[c], 16, 64);
        pA[c] += __shfl_xor(pA[c], 32, 64);
        pB[c] += __shfl_xor(pB[c], 16, 64);
        pB[c] += __shfl_xor(pB[c], 32, 64);
    }
    if (l4 == 0) {
        #pragma unroll
        for (int c = 0; c < NC; ++c) { lgA[w][l15][c] = pA[c]; lgB[w][l15][c] = pB[c]; }
    }
    __syncthreads();

    if (tid < 32) {
        const int tile = tid >> 4, bi = tid & 15;
        float l[NC];
        #pragma unroll
        for (int c = 0; c < NC; ++c) {
            l[c] = bdg[c];
            #pragma unroll
            for (int ww = 0; ww < 8; ++ww)
                l[c] += tile ? lgB[ww][bi][c] : lgA[ww][bi][c];
        }
        float m = l[0];
        #pragma unroll
        for (int c = 1; c < NC; ++c) m = fmaxf(m, l[c]);
        float e[NC], ssum = 0.0f;
        #pragma unroll
        for (int c = 0; c < NC; ++c) { e[c] = __expf(l[c] - m); ssum += e[c]; }
        const float rs = 1.0f / ssum;
        #pragma unroll
        for (int c = 0; c < NC; ++c)
            outg[(long)(b0 + tile*16 + bi)*NC + c] = e[c] * rs;
    }
}

extern "C" void kernel_launch(void* const* d_in, const int* in_sizes, int n_in,
                              void* d_out, int out_size, void* d_ws, size_t ws_size,
                              hipStream_t stream) {
    const float* x  = (const float*)d_in[0];  // [8192][187][1]
    const float* W  = (const float*)d_in[1];  // [1][128]
    const float* U  = (const float*)d_in[2];  // [128][128]
    const float* b  = (const float*)d_in[3];  // [128]
    const float* Wd = (const float*)d_in[4];  // [128][5]
    const float* bd = (const float*)d_in[5];  // [5]
    float* out = (float*)d_out;               // [8192][5]

    rnn_fused<<<BT / 32, 512, 0, stream>>>(x, W, U, b, Wd, bd, out);
}

// Round 11
// 89.087 us; speedup vs baseline: 1.0273x; 1.0273x over previous
//
#include <hip/hip_runtime.h>
#include <hip/hip_bf16.h>

// SimpleRNN(tanh) + Dense(5) + softmax, fused. B=8192, T=187, D=1, H=128, C=5.
//
// R11: 4 independent barrier streams per CU. 4 waves/block (256 thr), wave w
// owns 32 hidden rows [32w,32w+32); grid 512 -> 4 blocks/CU (launch_bounds
// (256,4)), 16 waves/CU = 4/SIMD, per-batch issue identical to R8 but with
// 4 decorrelated barriers filling each other's bubbles (R10 lesson: streams
// must be separate waves/blocks, never one wave's program order).
// 8 MFMA/wave/step as FOUR independent depth-2 chains. Full-fragment
// exchange: one ds_write_b128 + 4 ds_read_b128 per wave per step.
// Diet: U,W,b prescaled by 2*log2(e) -> tanh = exp2,add,rcp,fma (no mul);
// bias rides one chain's C operand (no zero-init).
// D-frag(step s) == B-frag(step s+1) in-lane (R1-validated mapping:
// F[e] = acc_{jt=e>>2}[e&3]). No dynamic register-array indexing.

#define BT 8192
#define TS 187
#define HD 128
#define NC 5

typedef float    f32x4  __attribute__((ext_vector_type(4)));
typedef _Float16 f16x8  __attribute__((ext_vector_type(8)));
typedef __fp16   fp16x2 __attribute__((ext_vector_type(2)));   // cvt_pkrtz return
typedef unsigned int u32;
typedef u32      u32x4  __attribute__((ext_vector_type(4)));

// Prescale U,W,b by PRE = 2*log2(e): MFMA yields v' = PRE*v and
// tanh(v) = 1 - 2/(2^(v') + 1).
#define PRE 2.885390081777927f

__device__ __forceinline__ float exp2_fast(float v) {
#if __has_builtin(__builtin_amdgcn_exp2f)
    return __builtin_amdgcn_exp2f(v);
#else
    return exp2f(v);
#endif
}

__device__ __forceinline__ float tanh_pre(float vp) {
    // vp = PRE*v; tanh(v) = 1 - 2/(2^vp + 1); exact at +-inf, no NaN.
    float e = exp2_fast(vp);
    float r = __builtin_amdgcn_rcpf(e + 1.0f);
    return fmaf(-2.0f, r, 1.0f);
}

__device__ __forceinline__ u32 pk16(float a, float b) {
    fp16x2 p = __builtin_amdgcn_cvt_pkrtz(a, b);
    return __builtin_bit_cast(u32, p);
}

union frag_u { f16x8 v; u32 w[4]; };

__device__ __forceinline__ void pin_frag(f16x8& f) {
    frag_u pu; pu.v = f;
    asm volatile("" : "+v"(pu.w[0]), "+v"(pu.w[1]), "+v"(pu.w[2]), "+v"(pu.w[3]));
    f = pu.v;
}

__global__ __launch_bounds__(256, 4)
void rnn_fused(const float* __restrict__ xg, const float* __restrict__ wg,
               const float* __restrict__ ug, const float* __restrict__ bg,
               const float* __restrict__ wdg, const float* __restrict__ bdg,
               float* __restrict__ outg)
{
    __shared__ u32   xb[2][4][64][4];   // [dbuf][frag T][lane][dword], 8 KB
    __shared__ float xs[TS][16];        // staged x, ~12 KB
    __shared__ float lg[4][16][NC];     // head partials

    const int tid  = threadIdx.x;
    const int w    = tid >> 6;          // wave 0..3 owns j in [32w, 32w+32)
    const int lane = tid & 63;
    const int l15  = lane & 15;         // batch col / j col for A-frag
    const int l4   = lane >> 4;         // 0..3
    const int b0   = blockIdx.x * 16;   // batch group

    // ---- stage x into LDS (one-time, coalesced along time)
    #pragma unroll
    for (int r = 0; r < 12; ++r) {
        const int idx = r * 256 + tid;          // 12*256 = 3072 = 16*192
        const int bb  = idx / 192;              // 0..15
        const int ss  = idx % 192;
        if (ss < TS)
            xs[ss][bb] = xg[(long)(b0 + bb) * TS + ss];
    }

    // ---- U^T fragments (prescaled fp16). A-frag (M=j, K=i):
    //   m=l15 -> j = 32w + 16jt + l15 ; elem e -> i = 32T + 16(e>>2)+4l4+(e&3)
    f16x8 uf00, uf01, uf02, uf03;   // jt=0, K-tiles 0..3
    f16x8 uf10, uf11, uf12, uf13;   // jt=1
    {
        const int j0 = 32*w + l15;
        #pragma unroll
        for (int e = 0; e < 8; ++e) {
            const int i = 16*(e>>2) + 4*l4 + (e&3);
            uf00[e] = (_Float16)(PRE * ug[(i     )*HD + j0]);
            uf01[e] = (_Float16)(PRE * ug[(i + 32)*HD + j0]);
            uf02[e] = (_Float16)(PRE * ug[(i + 64)*HD + j0]);
            uf03[e] = (_Float16)(PRE * ug[(i + 96)*HD + j0]);
            uf10[e] = (_Float16)(PRE * ug[(i     )*HD + j0 + 16]);
            uf11[e] = (_Float16)(PRE * ug[(i + 32)*HD + j0 + 16]);
            uf12[e] = (_Float16)(PRE * ug[(i + 64)*HD + j0 + 16]);
            uf13[e] = (_Float16)(PRE * ug[(i + 96)*HD + j0 + 16]);
        }
    }
    pin_frag(uf00); pin_frag(uf01); pin_frag(uf02); pin_frag(uf03);
    pin_frag(uf10); pin_frag(uf11); pin_frag(uf12); pin_frag(uf13);

    // ---- per-lane W, b (prescaled); b rides chain-b's C operand
    float wv0[4], wv1[4]; f32x4 bv0, bv1;
    #pragma unroll
    for (int q = 0; q < 4; ++q) {
        const int j = 32*w + 4*l4 + q;
        wv0[q] = PRE * wg[j];      bv0[q] = PRE * bg[j];
        wv1[q] = PRE * wg[j + 16]; bv1[q] = PRE * bg[j + 16];
    }

    // ---- state: h fragments (B layout), h0 = 0
    f16x8 h0 = (f16x8)(_Float16)0.0f;
    f16x8 h1 = h0, h2 = h0, h3 = h0;

    __syncthreads();                    // xs ready
    float xv = xs[0][l15];

    f32x4 accA, accB;   // post-tanh h (jt=0 / jt=1) persists for epilogue

    // One step; BUF compile-time. 4 independent depth-2 MFMA chains.
#define STEP(BUF, SN)                                                         \
    {                                                                         \
        const float xnext = xs[(SN)][l15];                                    \
        f32x4 a0, a1, b0c, b1c;                                               \
        _Pragma("unroll") for (int q = 0; q < 4; ++q) {                       \
            a0[q] = xv * wv0[q]; b0c[q] = xv * wv1[q];                        \
        }                                                                     \
        a0  = __builtin_amdgcn_mfma_f32_16x16x32_f16(uf00, h0, a0,  0, 0, 0); \
        b0c = __builtin_amdgcn_mfma_f32_16x16x32_f16(uf10, h0, b0c, 0, 0, 0); \
        a1  = __builtin_amdgcn_mfma_f32_16x16x32_f16(uf02, h2, bv0, 0, 0, 0); \
        b1c = __builtin_amdgcn_mfma_f32_16x16x32_f16(uf12, h2, bv1, 0, 0, 0); \
        a0  = __builtin_amdgcn_mfma_f32_16x16x32_f16(uf01, h1, a0,  0, 0, 0); \
        b0c = __builtin_amdgcn_mfma_f32_16x16x32_f16(uf11, h1, b0c, 0, 0, 0); \
        a1  = __builtin_amdgcn_mfma_f32_16x16x32_f16(uf03, h3, a1,  0, 0, 0); \
        b1c = __builtin_amdgcn_mfma_f32_16x16x32_f16(uf13, h3, b1c, 0, 0, 0); \
        _Pragma("unroll") for (int q = 0; q < 4; ++q) {                       \
            accA[q] = tanh_pre(a0[q] + a1[q]);                                \
            accB[q] = tanh_pre(b0c[q] + b1c[q]);                              \
        }                                                                     \
        u32x4 F;                                                              \
        F[0] = pk16(accA[0], accA[1]); F[1] = pk16(accA[2], accA[3]);         \
        F[2] = pk16(accB[0], accB[1]); F[3] = pk16(accB[2], accB[3]);         \
        *(u32x4*)&xb[(BUF)][w][lane][0] = F;                                  \
        __syncthreads();                                                      \
        h0 = *(const f16x8*)&xb[(BUF)][0][lane][0];                           \
        h1 = *(const f16x8*)&xb[(BUF)][1][lane][0];                           \
        h2 = *(const f16x8*)&xb[(BUF)][2][lane][0];                           \
        h3 = *(const f16x8*)&xb[(BUF)][3][lane][0];                           \
        xv = xnext;                                                           \
    }

    for (int k = 0; k < 93; ++k) {      // steps 0..185 as 93 unrolled pairs
        STEP(0, 2*k + 1);
        STEP(1, 2*k + 2);
    }
    STEP(0, TS - 1);                    // step 186 (dummy prefetch)
#undef STEP

    // ---- head: logits = h @ Wd + bd ; softmax over 5 ----
    float p[NC];
    #pragma unroll
    for (int c = 0; c < NC; ++c) p[c] = 0.0f;
    #pragma unroll
    for (int q = 0; q < 4; ++q) {
        const int j = 32*w + 4*l4 + q;
        #pragma unroll
        for (int c = 0; c < NC; ++c) {
            p[c] = fmaf(accA[q], wdg[j*NC + c], p[c]);
            p[c] = fmaf(accB[q], wdg[(j+16)*NC + c], p[c]);
        }
    }
    #pragma unroll
    for (int c = 0; c < NC; ++c) {      // reduce over l4 groups
        p[c] += __shfl_xor(p[c], 16, 64);
        p[c] += __shfl_xor(p[c], 32, 64);
    }
    if (l4 == 0) {
        #pragma unroll
        for (int c = 0; c < NC; ++c) lg[w][l15][c] = p[c];
    }
    __syncthreads();

    if (tid < 16) {
        float l[NC];
        #pragma unroll
        for (int c = 0; c < NC; ++c)
            l[c] = bdg[c] + lg[0][tid][c] + lg[1][tid][c] + lg[2][tid][c] + lg[3][tid][c];
        float m = l[0];
        #pragma unroll
        for (int c = 1; c < NC; ++c) m = fmaxf(m, l[c]);
        float e[NC], ssum = 0.0f;
        #pragma unroll
        for (int c = 0; c < NC; ++c) { e[c] = __expf(l[c] - m); ssum += e[c]; }
        const float rs = 1.0f / ssum;
        #pragma unroll
        for (int c = 0; c < NC; ++c)
            outg[(long)(b0 + tid)*NC + c] = e[c] * rs;
    }
}

extern "C" void kernel_launch(void* const* d_in, const int* in_sizes, int n_in,
                              void* d_out, int out_size, void* d_ws, size_t ws_size,
                              hipStream_t stream) {
    const float* x  = (const float*)d_in[0];  // [8192][187][1]
    const float* W  = (const float*)d_in[1];  // [1][128]
    const float* U  = (const float*)d_in[2];  // [128][128]
    const float* b  = (const float*)d_in[3];  // [128]
    const float* Wd = (const float*)d_in[4];  // [128][5]
    const float* bd = (const float*)d_in[5];  // [5]
    float* out = (float*)d_out;               // [8192][5]

    rnn_fused<<<BT / 16, 256, 0, stream>>>(x, W, U, b, Wd, bd, out);
}